// Round 2
// baseline (464.942 us; speedup 1.0000x reference)
//
#include <hip/hip_runtime.h>

// out[m][n] = C[m][n] * D[n];  M = NR = 8192, fp32 in/out.
// Memory-bound broadcast multiply: 268 MB read + 268 MB write.
// Roofline @ measured copy ceiling 6.29 TB/s = ~85 us.
//
// Structure: flat grid-stride copy-multiply matching the float4-copy ubench:
// 2048 blocks x 256 threads, stride 2^19 float4s, 32 contiguous 8 MB sweeps.
// Stride is a multiple of NR/4 -> each thread's column is invariant, so the
// D scale factor is loaded ONCE into registers. Plain (cached) loads/stores:
// nothing is reused except D, so there is no L2 pollution worth avoiding,
// and the 6.3-6.5 TB/s ubench ceilings were measured with plain accesses.

#define NR 8192
#define M_ROWS 8192
#define NC4 (NR / 4)                    // 2048 float4 per row
#define N4 ((M_ROWS * NR) / 4)          // 16,777,216 float4 total
#define THREADS 256
#define BLOCKS 2048                     // 8 blocks/CU co-resident
#define STRIDE (THREADS * BLOCKS)       // 524,288 float4s = 8 MB per sweep
#define ITERS (N4 / STRIDE)             // 32

typedef float v4 __attribute__((ext_vector_type(4)));

__global__ __launch_bounds__(256) void colscale_kernel(
    const v4* __restrict__ C4,
    const v4* __restrict__ D4,
    v4* __restrict__ O4)
{
    const unsigned t = blockIdx.x * THREADS + threadIdx.x;   // 0 .. 524287
    const v4 d = D4[t & (NC4 - 1)];      // column invariant under stride: 1 load

#pragma unroll 8
    for (int k = 0; k < ITERS; ++k) {
        const size_t i = (size_t)t + (size_t)k * STRIDE;
        O4[i] = C4[i] * d;
    }
}

extern "C" void kernel_launch(void* const* d_in, const int* in_sizes, int n_in,
                              void* d_out, int out_size, void* d_ws, size_t ws_size,
                              hipStream_t stream) {
    const v4* C4 = (const v4*)d_in[0];
    const v4* D4 = (const v4*)d_in[1];
    v4* O4 = (v4*)d_out;

    colscale_kernel<<<BLOCKS, THREADS, 0, stream>>>(C4, D4, O4);
}

// Round 5
// 423.680 us; speedup vs baseline: 1.0974x; 1.0974x over previous
//
#include <hip/hip_runtime.h>

// out[m][n] = C[m][n] * D[n];  M = NR = 8192, fp32 in/out.
// Memory-bound broadcast multiply: 268 MB read + 268 MB write.
//
// Round-2 counters showed FETCH_SIZE = 134 MB = C/2: the 256 MB Infinity
// Cache keeps ~half of C resident across the replay loop, evicted by the O
// write stream allocating into the cache. Fix: cache-stream separation —
// plain (cached) C loads keep C LLC-resident; NONTEMPORAL O stores keep the
// single-use write stream out of the LLC. HBM then carries mostly the 268 MB
// write stream -> kernel can beat the 85us copy roofline.
//
// Structure = best-measured one-shot layout (65,536 blocks x 256 thr x one
// float4, fully coalesced); the ONLY change vs that baseline is the nt store.
// Single kernel launch: multi-launch kernel_launch failed the harness 2/2.

#define NR 8192
#define M_ROWS 8192
#define NC4 (NR / 4)                    // 2048 float4 per row
#define N4 ((M_ROWS * NR) / 4)          // 16,777,216 float4 total
#define THREADS 256

typedef float v4 __attribute__((ext_vector_type(4)));

__global__ __launch_bounds__(256) void colscale_kernel(
    const v4* __restrict__ C4,
    const v4* __restrict__ D4,
    v4* __restrict__ O4)
{
    const unsigned i = blockIdx.x * THREADS + threadIdx.x;
    const v4 c = C4[i];                  // cached: keep C in LLC
    const v4 d = D4[i & (NC4 - 1)];      // tiny, L1/L2-resident
    __builtin_nontemporal_store(c * d, &O4[i]);   // nt: keep O out of LLC
}

extern "C" void kernel_launch(void* const* d_in, const int* in_sizes, int n_in,
                              void* d_out, int out_size, void* d_ws, size_t ws_size,
                              hipStream_t stream) {
    const v4* C4 = (const v4*)d_in[0];
    const v4* D4 = (const v4*)d_in[1];
    v4* O4 = (v4*)d_out;

    colscale_kernel<<<N4 / THREADS, THREADS, 0, stream>>>(C4, D4, O4);
}